// Round 1
// baseline (414.348 us; speedup 1.0000x reference)
//
#include <hip/hip_runtime.h>

// CoPE2d: B=64, NH=16, Wh=Ww=16, N=256, C=64, NPOS=288
// Layout: query (BH,256,64) f32; attn_logits (BH,256,256) f32;
//         pos_emb (64,288) f32; out (BH,256,256) f32.  BH = 1024.
// One block per (bh, p) where p = 16-row block. 320 threads (5 waves).

#define NPOS 288

__global__ __launch_bounds__(320, 3) void cope2d_kernel(
    const float* __restrict__ query,
    const float* __restrict__ attn_logits,
    const float* __restrict__ pos_emb,
    float* __restrict__ out)
{
    __shared__ float Ltab[16 * NPOS];   // 18432 B: logits_int rows for this block

    const int tid = threadIdx.x;
    const int blk = blockIdx.x;
    const int bh  = blk >> 4;           // 0..1023
    const int p   = blk & 15;           // row-block
    const long rowbase = (long)bh * 256 + p * 16;   // first global row n0

    // ---------------- GEMM: Ltab[i][t] = sum_c q[n0+i][c] * P[c][t] ----------
    // thread t = tid (t < 288) owns one pos_emb column in registers.
    if (tid < NPOS) {
        float pc[64];
        #pragma unroll
        for (int c = 0; c < 64; ++c)
            pc[c] = pos_emb[c * NPOS + tid];        // coalesced, L2-resident

        const float* qbase = query + rowbase * 64;  // wave-uniform address
        #pragma unroll
        for (int i = 0; i < 16; ++i) {
            const float* qr = qbase + i * 64;       // uniform -> s_load expected
            float a0 = 0.f, a1 = 0.f, a2 = 0.f, a3 = 0.f;
            #pragma unroll
            for (int c = 0; c < 64; c += 4) {
                a0 = fmaf(qr[c + 0], pc[c + 0], a0);
                a1 = fmaf(qr[c + 1], pc[c + 1], a1);
                a2 = fmaf(qr[c + 2], pc[c + 2], a2);
                a3 = fmaf(qr[c + 3], pc[c + 3], a3);
            }
            Ltab[i * NPOS + tid] = (a0 + a1) + (a2 + a3);
        }
    }
    __syncthreads();

    // ---------------- gates -> pos_h/pos_w -> gather+lerp -> out -------------
    if (tid < 256) {
        const int j = tid;                  // column owned by this thread
        const int lane = tid & 63;
        const long gbase = rowbase * 256;   // base into attn_logits / out

        float acc_h = 0.f;                  // suffix sum over rows (pos_h)
        #pragma unroll
        for (int i = 15; i >= 0; --i) {
            float x = attn_logits[gbase + (long)i * 256 + j];  // coalesced
            float g = 1.0f / (1.0f + __expf(-x));              // sigmoid
            acc_h += g;                                        // pos_h (inclusive)

            // pos_w: inclusive suffix scan within aligned 16-lane groups
            float pw = g;
            #pragma unroll
            for (int d = 1; d < 16; d <<= 1) {
                float o = __shfl_down(pw, d, 16);
                if ((lane & 15) + d < 16) pw += o;
            }

            float pos = acc_h * 16.0f + pw;
            pos = fminf(pos, 287.0f);       // npos_max-1 (never binds: pos < 272)
            float pf = floorf(pos);
            int   fi = (int)pf;
            float w  = pos - pf;

            const float* Lrow = Ltab + i * NPOS;
            float lf = Lrow[fi];
            float lc = Lrow[fi + 1];        // ceil==floor only when w==0: exact
            out[gbase + (long)i * 256 + j] = lf + w * (lc - lf);
        }
    }
}

extern "C" void kernel_launch(void* const* d_in, const int* in_sizes, int n_in,
                              void* d_out, int out_size, void* d_ws, size_t ws_size,
                              hipStream_t stream) {
    const float* query       = (const float*)d_in[0];
    const float* attn_logits = (const float*)d_in[1];
    const float* pos_emb     = (const float*)d_in[2];
    float* outp = (float*)d_out;

    // grid: BH(1024) * 16 row-blocks
    cope2d_kernel<<<16384, 320, 0, stream>>>(query, attn_logits, pos_emb, outp);
}